// Round 7
// baseline (465.597 us; speedup 1.0000x reference)
//
#include <hip/hip_runtime.h>

constexpr int NBINS = 256;
constexpr int HPI = 3 * NBINS;  // 768 bins per image (3 channels)
constexpr int BPI = 24;         // blocks per image; 64*24=1536 = exactly 6 blocks/CU

typedef int iv4 __attribute__((ext_vector_type(4)));

// Single fused kernel: partial hist -> per-image handshake -> LUT -> apply.
// Co-residency of all 1536 blocks is guaranteed: launch_bounds(256,6) gives
// >=6 blocks/CU (VGPR), LDS 16.4KB*6=99KB<160KB, threads 6*256<2048, so the
// per-image spin cannot deadlock.
__global__ __launch_bounds__(256, 6)
void equalize_onepass(const iv4* __restrict__ in, iv4* __restrict__ out,
                      int* __restrict__ part, int* __restrict__ flags,
                      int n4_per_img) {
    __shared__ int subh[4][HPI];   // 12.3 KB per-wave sub-histograms
    __shared__ int cum[NBINS];
    __shared__ int lutS[HPI];
    __shared__ int lastNZ;

    const int tid  = threadIdx.x;
    const int wave = tid >> 6;
    const int img  = blockIdx.x / BPI;
    const int blk  = blockIdx.x % BPI;

    for (int i = tid; i < 4 * HPI; i += 256) ((int*)subh)[i] = 0;
    __syncthreads();

    const iv4* p = in + (size_t)img * n4_per_img;
    const int stride = BPI * 256;  // 6144, divisible by 3 -> channel phase loop-invariant

    // channel of element 4*i is i % 3
    int i = blk * 256 + tid;
    int c0 = i % 3;
    int c1 = c0 + 1; if (c1 == 3) c1 = 0;
    int c2 = c1 + 1; if (c2 == 3) c2 = 0;
    int c3 = c2 + 1; if (c3 == 3) c3 = 0;
    const int b0 = c0 * NBINS, b1 = c1 * NBINS, b2 = c2 * NBINS, b3 = c3 * NBINS;
    const int istart = i;

    // ---- Phase 1: histogram (unroll x2 for ILP) ----
    for (; i + stride < n4_per_img; i += 2 * stride) {
        iv4 v0 = p[i];
        iv4 v1 = p[i + stride];
        atomicAdd(&subh[wave][b0 + (v0.x & 255)], 1);
        atomicAdd(&subh[wave][b1 + (v0.y & 255)], 1);
        atomicAdd(&subh[wave][b2 + (v0.z & 255)], 1);
        atomicAdd(&subh[wave][b3 + (v0.w & 255)], 1);
        atomicAdd(&subh[wave][b0 + (v1.x & 255)], 1);
        atomicAdd(&subh[wave][b1 + (v1.y & 255)], 1);
        atomicAdd(&subh[wave][b2 + (v1.z & 255)], 1);
        atomicAdd(&subh[wave][b3 + (v1.w & 255)], 1);
    }
    if (i < n4_per_img) {
        iv4 v = p[i];
        atomicAdd(&subh[wave][b0 + (v.x & 255)], 1);
        atomicAdd(&subh[wave][b1 + (v.y & 255)], 1);
        atomicAdd(&subh[wave][b2 + (v.z & 255)], 1);
        atomicAdd(&subh[wave][b3 + (v.w & 255)], 1);
    }
    __syncthreads();

    // ---- Publish partial histogram (plain stores + release) ----
    int* gp = part + (size_t)blockIdx.x * HPI;
    for (int e = tid; e < HPI; e += 256)
        gp[e] = subh[0][e] + subh[1][e] + subh[2][e] + subh[3][e];
    __threadfence();   // each thread makes its stores device-visible
    __syncthreads();   // all fences done
    if (tid == 0) {
        atomicAdd(&flags[img], 1);  // device-scope
        // ---- Per-image handshake: wait for all 24 sibling partials ----
        while (__hip_atomic_load(&flags[img], __ATOMIC_ACQUIRE,
                                 __HIP_MEMORY_SCOPE_AGENT) < BPI)
            __builtin_amdgcn_s_sleep(2);
    }
    __syncthreads();
    __threadfence();   // invalidate stale cache lines before reading partials

    // ---- Phase 2: reduce partials + build 3-channel LUT (redundant per block, cheap) ----
    const int* pp = part + (size_t)img * BPI * HPI;
    int h[3];
    #pragma unroll
    for (int ch = 0; ch < 3; ++ch) {
        int s = 0;
        for (int b = 0; b < BPI; ++b) s += pp[b * HPI + ch * NBINS + tid];  // coalesced
        h[ch] = s;
    }

    #pragma unroll
    for (int ch = 0; ch < 3; ++ch) {
        if (tid == 0) lastNZ = 0;
        cum[tid] = h[ch];
        __syncthreads();
        if (h[ch] > 0) atomicMax(&lastNZ, tid);

        for (int off = 1; off < NBINS; off <<= 1) {
            int add = (tid >= off) ? cum[tid - off] : 0;
            __syncthreads();
            cum[tid] += add;
            __syncthreads();
        }

        const int sum  = cum[NBINS - 1];
        const int last = lastNZ;
        const int hl   = cum[last] - (last > 0 ? cum[last - 1] : 0);  // histo[last]
        const int step = (sum - hl) / 255;

        int v;
        if (step == 0) {
            v = tid;  // reference: where(step==0, img, ...)
        } else {
            // lut = clip(concat([0], (cumsum+step//2)//step [:-1]), 0, 255)
            const int cp = (tid == 0) ? 0 : cum[tid - 1];
            v = (cp + (step >> 1)) / step;
            if (v > 255) v = 255;
        }
        lutS[ch * NBINS + tid] = v;
        __syncthreads();  // cum/lastNZ reused next channel; lutS visible for apply
    }

    // ---- Phase 3: apply (input re-read is LLC-resident), nt-store output ----
    iv4* q = out + (size_t)img * n4_per_img;
    i = istart;
    for (; i + stride < n4_per_img; i += 2 * stride) {
        iv4 v0 = p[i];
        iv4 v1 = p[i + stride];
        iv4 o0, o1;
        o0.x = lutS[b0 + (v0.x & 255)];
        o0.y = lutS[b1 + (v0.y & 255)];
        o0.z = lutS[b2 + (v0.z & 255)];
        o0.w = lutS[b3 + (v0.w & 255)];
        o1.x = lutS[b0 + (v1.x & 255)];
        o1.y = lutS[b1 + (v1.y & 255)];
        o1.z = lutS[b2 + (v1.z & 255)];
        o1.w = lutS[b3 + (v1.w & 255)];
        __builtin_nontemporal_store(o0, &q[i]);           // never re-read:
        __builtin_nontemporal_store(o1, &q[i + stride]);  // keep LLC for input
    }
    if (i < n4_per_img) {
        iv4 v = p[i];
        iv4 o;
        o.x = lutS[b0 + (v.x & 255)];
        o.y = lutS[b1 + (v.y & 255)];
        o.z = lutS[b2 + (v.z & 255)];
        o.w = lutS[b3 + (v.w & 255)];
        __builtin_nontemporal_store(o, &q[i]);
    }
}

extern "C" void kernel_launch(void* const* d_in, const int* in_sizes, int n_in,
                              void* d_out, int out_size, void* d_ws, size_t ws_size,
                              hipStream_t stream) {
    const int* in = (const int*)d_in[0];
    int* out = (int*)d_out;

    const int npix = 512 * 512;
    const int ints_per_img = 3 * npix;
    const int n4_per_img = ints_per_img / 4;        // 196608 (= 32 * 6144 exactly)
    const int n_img = in_sizes[0] / ints_per_img;   // 64

    int* part  = (int*)d_ws;                            // 1536*768 ints = 4.7 MB
    int* flags = part + (size_t)n_img * BPI * HPI;      // 64 ints

    hipMemsetAsync(flags, 0, (size_t)n_img * sizeof(int), stream);

    equalize_onepass<<<n_img * BPI, 256, 0, stream>>>(
        (const iv4*)in, (iv4*)out, part, flags, n4_per_img);
}

// Round 8
// 86.672 us; speedup vs baseline: 5.3719x; 5.3719x over previous
//
#include <hip/hip_runtime.h>

constexpr int NBINS = 256;
constexpr int HPI = 3 * NBINS;  // 768 bins per image (3 channels)
constexpr int BPI = 24;         // blocks per image: 64*24=1536 = exactly 6 blocks/CU

typedef int iv4 __attribute__((ext_vector_type(4)));

// ---------------- Kernel 1: partial histograms + packed uint8 copy ----------------
// Element index of v.x is 4*i; (4*i) % 3 == i % 3. stride % 3 == 0 keeps the
// channel phase loop-invariant. Also emits a 4x-compressed copy of the image
// so the apply kernel reads 50 MB (L3-resident) instead of 201 MB.
__global__ __launch_bounds__(256)
void hist_part_kernel(const iv4* __restrict__ in, int* __restrict__ part,
                      unsigned* __restrict__ packed, int n4_per_img) {
    __shared__ int subh[4][HPI];  // per-wave sub-histograms, 12 KB
    const int tid = threadIdx.x;
    const int wave = tid >> 6;

    for (int i = tid; i < 4 * HPI; i += 256) ((int*)subh)[i] = 0;
    __syncthreads();

    const int img = blockIdx.x / BPI;
    const int blk = blockIdx.x % BPI;
    const size_t ibase = (size_t)img * n4_per_img;
    const iv4* p = in + ibase;
    unsigned* pk = packed + ibase;
    const int stride = BPI * 256;  // 6144, divisible by 3

    int i = blk * 256 + tid;
    int c0 = i % 3;
    int c1 = c0 + 1; if (c1 == 3) c1 = 0;
    int c2 = c1 + 1; if (c2 == 3) c2 = 0;
    int c3 = c2 + 1; if (c3 == 3) c3 = 0;
    const int b0 = c0 * NBINS, b1 = c1 * NBINS, b2 = c2 * NBINS, b3 = c3 * NBINS;

    for (; i + stride < n4_per_img; i += 2 * stride) {
        iv4 v0 = p[i];
        iv4 v1 = p[i + stride];
        pk[i]          = (unsigned)(v0.x & 255) | ((unsigned)(v0.y & 255) << 8) |
                         ((unsigned)(v0.z & 255) << 16) | ((unsigned)(v0.w & 255) << 24);
        pk[i + stride] = (unsigned)(v1.x & 255) | ((unsigned)(v1.y & 255) << 8) |
                         ((unsigned)(v1.z & 255) << 16) | ((unsigned)(v1.w & 255) << 24);
        atomicAdd(&subh[wave][b0 + (v0.x & 255)], 1);
        atomicAdd(&subh[wave][b1 + (v0.y & 255)], 1);
        atomicAdd(&subh[wave][b2 + (v0.z & 255)], 1);
        atomicAdd(&subh[wave][b3 + (v0.w & 255)], 1);
        atomicAdd(&subh[wave][b0 + (v1.x & 255)], 1);
        atomicAdd(&subh[wave][b1 + (v1.y & 255)], 1);
        atomicAdd(&subh[wave][b2 + (v1.z & 255)], 1);
        atomicAdd(&subh[wave][b3 + (v1.w & 255)], 1);
    }
    if (i < n4_per_img) {
        iv4 v = p[i];
        pk[i] = (unsigned)(v.x & 255) | ((unsigned)(v.y & 255) << 8) |
                ((unsigned)(v.z & 255) << 16) | ((unsigned)(v.w & 255) << 24);
        atomicAdd(&subh[wave][b0 + (v.x & 255)], 1);
        atomicAdd(&subh[wave][b1 + (v.y & 255)], 1);
        atomicAdd(&subh[wave][b2 + (v.z & 255)], 1);
        atomicAdd(&subh[wave][b3 + (v.w & 255)], 1);
    }
    __syncthreads();

    int* gp = part + (size_t)blockIdx.x * HPI;  // own slot: plain store, no atomics
    for (int e = tid; e < HPI; e += 256)
        gp[e] = subh[0][e] + subh[1][e] + subh[2][e] + subh[3][e];
}

// ---------------- Kernel 2: reduce partials + build LUT per (img,channel) ----------------
__global__ __launch_bounds__(256)
void lut_kernel(const int* __restrict__ part, int* __restrict__ lut) {
    __shared__ int cum[NBINS];
    __shared__ int lastNZ;
    const int t = threadIdx.x;
    const int img = blockIdx.x / 3;
    const int ch  = blockIdx.x % 3;

    const int* p = part + (size_t)img * BPI * HPI + ch * NBINS + t;
    int h = 0;
    for (int b = 0; b < BPI; ++b) h += p[(size_t)b * HPI];

    cum[t] = h;
    if (t == 0) lastNZ = 0;
    __syncthreads();
    if (h > 0) atomicMax(&lastNZ, t);

    for (int off = 1; off < NBINS; off <<= 1) {
        int add = (t >= off) ? cum[t - off] : 0;
        __syncthreads();
        cum[t] += add;
        __syncthreads();
    }

    const int sum  = cum[NBINS - 1];
    const int last = lastNZ;
    const int hl   = cum[last] - (last > 0 ? cum[last - 1] : 0);  // histo[last]
    const int step = (sum - hl) / 255;

    int v;
    if (step == 0) {
        v = t;  // reference: where(step==0, img, ...)
    } else {
        // lut = clip(concat([0], (cumsum+step//2)//step [:-1]), 0, 255)
        const int cp = (t == 0) ? 0 : cum[t - 1];
        v = (cp + (step >> 1)) / step;
        if (v > 255) v = 255;
    }
    lut[blockIdx.x * NBINS + t] = v;
}

// ---------------- Kernel 3: apply LUT from packed uint8, nt-int4 out ----------------
__global__ __launch_bounds__(256)
void apply_kernel(const unsigned* __restrict__ packed, iv4* __restrict__ out,
                  const int* __restrict__ lut, int n4_per_img) {
    __shared__ int l[HPI];
    const int tid = threadIdx.x;
    const int img = blockIdx.x / BPI;
    const int blk = blockIdx.x % BPI;

    const int* gl = lut + (size_t)img * HPI;
    for (int i = tid; i < HPI; i += 256) l[i] = gl[i];
    __syncthreads();

    const size_t ibase = (size_t)img * n4_per_img;
    const unsigned* pk = packed + ibase;
    iv4* q = out + ibase;
    const int stride = BPI * 256;  // divisible by 3

    int i = blk * 256 + tid;
    int c0 = i % 3;
    int c1 = c0 + 1; if (c1 == 3) c1 = 0;
    int c2 = c1 + 1; if (c2 == 3) c2 = 0;
    int c3 = c2 + 1; if (c3 == 3) c3 = 0;
    const int b0 = c0 * NBINS, b1 = c1 * NBINS, b2 = c2 * NBINS, b3 = c3 * NBINS;

    for (; i + stride < n4_per_img; i += 2 * stride) {
        unsigned w0 = pk[i];
        unsigned w1 = pk[i + stride];
        iv4 o0, o1;
        o0.x = l[b0 + (w0 & 255)];
        o0.y = l[b1 + ((w0 >> 8) & 255)];
        o0.z = l[b2 + ((w0 >> 16) & 255)];
        o0.w = l[b3 + (w0 >> 24)];
        o1.x = l[b0 + (w1 & 255)];
        o1.y = l[b1 + ((w1 >> 8) & 255)];
        o1.z = l[b2 + ((w1 >> 16) & 255)];
        o1.w = l[b3 + (w1 >> 24)];
        __builtin_nontemporal_store(o0, &q[i]);           // output never re-read:
        __builtin_nontemporal_store(o1, &q[i + stride]);  // don't pollute L2/LLC
    }
    if (i < n4_per_img) {
        unsigned w = pk[i];
        iv4 o;
        o.x = l[b0 + (w & 255)];
        o.y = l[b1 + ((w >> 8) & 255)];
        o.z = l[b2 + ((w >> 16) & 255)];
        o.w = l[b3 + (w >> 24)];
        __builtin_nontemporal_store(o, &q[i]);
    }
}

extern "C" void kernel_launch(void* const* d_in, const int* in_sizes, int n_in,
                              void* d_out, int out_size, void* d_ws, size_t ws_size,
                              hipStream_t stream) {
    const int* in = (const int*)d_in[0];
    int* out = (int*)d_out;

    const int npix = 512 * 512;
    const int ints_per_img = 3 * npix;
    const int n4_per_img = ints_per_img / 4;        // 196608 (= 32 * 6144 exactly)
    const int n_img = in_sizes[0] / ints_per_img;   // 64

    // ws layout: partials (4.7 MB) | lut (192 KB) | packed image copy (50 MB)
    int* part = (int*)d_ws;
    int* lut  = part + (size_t)n_img * BPI * HPI;
    unsigned* packed = (unsigned*)(lut + (size_t)n_img * HPI);

    hist_part_kernel<<<n_img * BPI, 256, 0, stream>>>((const iv4*)in, part, packed, n4_per_img);
    lut_kernel<<<n_img * 3, 256, 0, stream>>>(part, lut);
    apply_kernel<<<n_img * BPI, 256, 0, stream>>>(packed, (iv4*)out, lut, n4_per_img);
}